// Round 4
// baseline (801.304 us; speedup 1.0000x reference)
//
#include <hip/hip_runtime.h>
#include <math.h>

constexpr int SEQL = 128;
constexpr int NH   = 8;
constexpr int EMB  = 256;
constexpr int NB   = 64;
constexpr int CCH  = SEQL * NH;                // 1024
constexpr size_t SZ = (size_t)NB * CCH * EMB;  // 16,777,216 elements per plane

typedef short s16x8 __attribute__((ext_vector_type(8)));
typedef float f32x4 __attribute__((ext_vector_type(4)));
typedef unsigned short u16;

// ---- fp32 -> bf16 hi/lo split (RNE) ----
__device__ __forceinline__ unsigned int bfr(float f) {
    unsigned int u = __float_as_uint(f);
    return (u + 0x7fffu + ((u >> 16) & 1u)) >> 16;
}
__device__ __forceinline__ void split2(float v, u16& h, u16& l) {
    unsigned int hb = bfr(v);
    float fh = __uint_as_float(hb << 16);
    unsigned int lb = bfr(v - fh);
    h = (u16)hb; l = (u16)lb;
}
__device__ __forceinline__ float tob(u16 u) {
    return __uint_as_float((unsigned int)u << 16);
}

// ---------------------------------------------------------------------------
// Weight pre-transpose + split: W[k][n] fp32 -> Wt_hi[n][k], Wt_lo[n][k] bf16.
// ---------------------------------------------------------------------------
__global__ __launch_bounds__(256)
void wtconv(const float* __restrict__ s0, const float* __restrict__ s1,
            const float* __restrict__ s2, const float* __restrict__ s3,
            const float* __restrict__ s4, const float* __restrict__ s5,
            const float* __restrict__ s6, u16* __restrict__ dst)
{
    const int mat = blockIdx.x >> 7;
    const float* s = s0;
    if (mat == 1) s = s1; else if (mat == 2) s = s2; else if (mat == 3) s = s3;
    else if (mat == 4) s = s4; else if (mat == 5) s = s5; else if (mat == 6) s = s6;
    const int o = (blockIdx.x & 127) * 512 + threadIdx.x * 2;
    const int n = o >> 8, k = o & 255;
    float v0 = s[(size_t)k * 256 + n];
    float v1 = s[(size_t)(k + 1) * 256 + n];
    u16 h0, l0, h1, l1;
    split2(v0, h0, l0); split2(v1, h1, l1);
    u16* d = dst + (size_t)mat * 131072;
    *(unsigned int*)(d + (size_t)n * 256 + k)         = (unsigned int)h0 | ((unsigned int)h1 << 16);
    *(unsigned int*)(d + 65536 + (size_t)n * 256 + k) = (unsigned int)l0 | ((unsigned int)l1 << 16);
}

// colsum[n] = sum_k W[k][n] for the two BN-folded matrices
__global__ __launch_bounds__(256)
void colsum_k(const float* __restrict__ Wa, const float* __restrict__ Wb,
              float* __restrict__ ca, float* __restrict__ cb)
{
    const float* W = blockIdx.x ? Wb : Wa;
    float* o = blockIdx.x ? cb : ca;
    float s = 0.f;
    for (int k = 0; k < 256; ++k) s += W[(size_t)k * 256 + threadIdx.x];
    o[threadIdx.x] = s;
}

__global__ __launch_bounds__(256)
void prep_eh(const float* __restrict__ E, u16* __restrict__ eh)
{
    const int i = (blockIdx.x * 256 + threadIdx.x) * 4;
    float4 f = *(const float4*)(E + i);
    unsigned int p0 = bfr(f.x) | (bfr(f.y) << 16);
    unsigned int p1 = bfr(f.z) | (bfr(f.w) << 16);
    ((unsigned int*)eh)[(i >> 1)]     = p0;
    ((unsigned int*)eh)[(i >> 1) + 1] = p1;
}

__global__ __launch_bounds__(256)
void zero_stats(float* __restrict__ p) { p[blockIdx.x * 256 + threadIdx.x] = 0.f; }

__global__ __launch_bounds__(256)
void bn_finalize(const float* __restrict__ s, const float* __restrict__ q,
                 const float* __restrict__ w, const float* __restrict__ b,
                 float* __restrict__ alpha, float* __restrict__ beta)
{
    const int c = blockIdx.x * 256 + threadIdx.x;
    const float invN = 1.0f / 16384.0f;
    float mean = s[c] * invN;
    float var  = q[c] * invN - mean * mean;
    float a = rsqrtf(var + 1e-5f) * w[c];
    alpha[c] = a;
    beta[c]  = b[c] - mean * a;
}

// ---------------------------------------------------------------------------
// bf16x3 MFMA GEMM, 128x128 tile, 4 waves, BK=32, LDS stride 40 (2-way free).
// ASRC: 0 = fp32 A (split in staging), 1 = hi/lo planes (pure copy staging)
// BN:   fold input-BN: v = alf[c]*acc + bet[c]*wcol[col] + bias
// RESM: 0 none, 1 += resf (fp32), 2 += alr[c]*(resh+resl) + ber[c]
// STATS: accumulate per-channel sum/sumsq via shfl-reduce + atomics
// OUTM: 0 fp32, 1 hi/lo planes, 2 bf16-hi only
// ---------------------------------------------------------------------------
template<int ASRC, int BN, int ACT, int RESM, int STATS, int OUTM>
__global__ __launch_bounds__(256)
void mgemm(const float* __restrict__ Af,
           const u16* __restrict__ Aph, const u16* __restrict__ Apl,
           const u16* __restrict__ WtHi, const u16* __restrict__ WtLo,
           const float* __restrict__ bias,
           const float* __restrict__ resf,
           const u16* __restrict__ resh, const u16* __restrict__ resl,
           const float* __restrict__ alf, const float* __restrict__ bet,
           const float* __restrict__ wcol,
           const float* __restrict__ alr, const float* __restrict__ ber,
           float* __restrict__ statS, float* __restrict__ statQ,
           float* __restrict__ outf, u16* __restrict__ outh, u16* __restrict__ outl)
{
    __shared__ u16 Ahi[128 * 40];
    __shared__ u16 Alo[128 * 40];
    __shared__ u16 Bhi[128 * 40];
    __shared__ u16 Blo[128 * 40];

    const int tid = threadIdx.x;
    const int bid = blockIdx.x;
    const int wg  = (bid & 7) * (gridDim.x >> 3) + (bid >> 3);   // XCD swizzle
    const int m0 = (wg >> 1) * 128;
    const int n0 = (wg & 1) * 128;
    const int wave = tid >> 6, lane = tid & 63;
    const int wm = wave >> 1, wn = wave & 1;
    const int fr = lane & 15, g = lane >> 4;
    const int fk = g * 8;

    const int srow = tid >> 1;          // staging row 0..127
    const int scs  = (tid & 1) * 2;     // chunk base {0,2}, 8 u16 per chunk

    f32x4 acc[4][4] = {};

    for (int kt = 0; kt < 8; ++kt) {
        const int k0 = kt * 32;
        __syncthreads();
        // ---- stage A ----
        if (ASRC == 0) {
            const float* aptr = Af + (size_t)(m0 + srow) * 256 + (tid & 1) * 16 + k0;
            u16 hs[16], ls[16];
            #pragma unroll
            for (int q = 0; q < 4; ++q) {
                float4 f = *(const float4*)(aptr + q * 4);
                split2(f.x, hs[q*4+0], ls[q*4+0]);
                split2(f.y, hs[q*4+1], ls[q*4+1]);
                split2(f.z, hs[q*4+2], ls[q*4+2]);
                split2(f.w, hs[q*4+3], ls[q*4+3]);
            }
            u16* ah = Ahi + srow * 40 + (tid & 1) * 16;
            u16* al = Alo + srow * 40 + (tid & 1) * 16;
            *(uint4*)ah       = *(uint4*)&hs[0];
            *(uint4*)(ah + 8) = *(uint4*)&hs[8];
            *(uint4*)al       = *(uint4*)&ls[0];
            *(uint4*)(al + 8) = *(uint4*)&ls[8];
        } else {
            const size_t abase = (size_t)(m0 + srow) * 256 + k0;
            #pragma unroll
            for (int j = 0; j < 2; ++j) {
                *(uint4*)(Ahi + srow * 40 + (scs + j) * 8) = *(const uint4*)(Aph + abase + (scs + j) * 8);
                *(uint4*)(Alo + srow * 40 + (scs + j) * 8) = *(const uint4*)(Apl + abase + (scs + j) * 8);
            }
        }
        // ---- stage B (always planes) ----
        {
            const size_t bbase = (size_t)(n0 + srow) * 256 + k0;
            #pragma unroll
            for (int j = 0; j < 2; ++j) {
                *(uint4*)(Bhi + srow * 40 + (scs + j) * 8) = *(const uint4*)(WtHi + bbase + (scs + j) * 8);
                *(uint4*)(Blo + srow * 40 + (scs + j) * 8) = *(const uint4*)(WtLo + bbase + (scs + j) * 8);
            }
        }
        __syncthreads();
        // ---- compute ----
        s16x8 ahf[4], alf_[4];
        #pragma unroll
        for (int mf = 0; mf < 4; ++mf) {
            const int r = wm * 64 + mf * 16 + fr;
            ahf[mf]  = *(const s16x8*)(Ahi + r * 40 + fk);
            alf_[mf] = *(const s16x8*)(Alo + r * 40 + fk);
        }
        #pragma unroll
        for (int nf = 0; nf < 4; ++nf) {
            const int cc = wn * 64 + nf * 16 + fr;
            s16x8 bh = *(const s16x8*)(Bhi + cc * 40 + fk);
            s16x8 bl = *(const s16x8*)(Blo + cc * 40 + fk);
            #pragma unroll
            for (int mf = 0; mf < 4; ++mf) {
                acc[mf][nf] = __builtin_amdgcn_mfma_f32_16x16x32_bf16(ahf[mf],  bh, acc[mf][nf], 0, 0, 0);
                acc[mf][nf] = __builtin_amdgcn_mfma_f32_16x16x32_bf16(ahf[mf],  bl, acc[mf][nf], 0, 0, 0);
                acc[mf][nf] = __builtin_amdgcn_mfma_f32_16x16x32_bf16(alf_[mf], bh, acc[mf][nf], 0, 0, 0);
            }
        }
    }

    // ---- epilogue ----
    float sA[4][4], sQ[4][4];
    if (STATS) {
        #pragma unroll
        for (int mf = 0; mf < 4; ++mf)
            #pragma unroll
            for (int r = 0; r < 4; ++r) { sA[mf][r] = 0.f; sQ[mf][r] = 0.f; }
    }
    #pragma unroll
    for (int nf = 0; nf < 4; ++nf) {
        const int col = n0 + wn * 64 + nf * 16 + fr;
        const float bb = bias[col];
        const float wc = BN ? wcol[col] : 0.f;
        #pragma unroll
        for (int mf = 0; mf < 4; ++mf) {
            #pragma unroll
            for (int r = 0; r < 4; ++r) {
                const int row = m0 + wm * 64 + mf * 16 + g * 4 + r;
                const int c = row & 1023;
                float v = acc[mf][nf][r];
                if (BN) v = alf[c] * v + bet[c] * wc + bb;
                else    v += bb;
                if (RESM == 1) v += resf[(size_t)row * 256 + col];
                if (RESM == 2) {
                    const size_t ri = (size_t)row * 256 + col;
                    float rv = tob(resh[ri]) + tob(resl[ri]);
                    v += alr[c] * rv + ber[c];
                }
                if (ACT) v = v > 0.f ? v : 0.01f * v;
                if (STATS) { sA[mf][r] += v; sQ[mf][r] += v * v; }
                const size_t idx = (size_t)row * 256 + col;
                if (OUTM == 0) outf[idx] = v;
                else if (OUTM == 1) { u16 hh, ll; split2(v, hh, ll); outh[idx] = hh; outl[idx] = ll; }
                else outh[idx] = (u16)bfr(v);
            }
        }
    }
    if (STATS) {
        #pragma unroll
        for (int mf = 0; mf < 4; ++mf) {
            #pragma unroll
            for (int r = 0; r < 4; ++r) {
                float s = sA[mf][r], q = sQ[mf][r];
                #pragma unroll
                for (int o = 8; o > 0; o >>= 1) { s += __shfl_xor(s, o); q += __shfl_xor(q, o); }
                if (fr == 0) {
                    const int row = m0 + wm * 64 + mf * 16 + g * 4 + r;
                    atomicAdd(&statS[row & 1023], s);
                    atomicAdd(&statQ[row & 1023], q);
                }
            }
        }
    }
}

// ---------------------------------------------------------------------------
// MFMA attention, plane inputs/outputs. Block = (n, h, 64-q slab), 4 waves.
// att rows are wave-private (no barriers needed for att ordering).
// Vt staged in (l-half x e-half) quarters: LDS 53.2 KB -> 3 blocks/CU.
// Z planes alias Q planes (blocks write only their own fully-read rows).
// ---------------------------------------------------------------------------
__global__ __launch_bounds__(256)
void attn_mfma(const u16* __restrict__ Qh, const u16* __restrict__ Ql,
               const u16* __restrict__ Kh,
               const u16* __restrict__ Vh, const u16* __restrict__ Vl,
               const u16* __restrict__ Eh,
               u16* __restrict__ Zh, u16* __restrict__ Zl)
{
    __shared__ u16 att_h[64 * 136];
    __shared__ u16 att_l[64 * 136];
    __shared__ u16 Vt[128 * 72];         // [e-local 128][l-local 64 + pad]

    const int tid = threadIdx.x;
    const int n  = blockIdx.x >> 4;
    const int h  = (blockIdx.x >> 1) & 7;
    const int q0 = (blockIdx.x & 1) * 64;
    const int w = tid >> 6, lane = tid & 63;
    const int fr = lane & 15, g = lane >> 4;
    const int fk = g * 8;

    const size_t nb = (size_t)n * 1024 + h;
    #define GROW(s) ((nb + (size_t)(s) * 8) * 256)

    const int qa = q0 + 16 * w + fr;

    // ---------------- Phase 1: QK + in-register softmax -> P ----------------
    f32x4 acc[8];
    #pragma unroll
    for (int nf = 0; nf < 8; ++nf) acc[nf] = (f32x4){0.f, 0.f, 0.f, 0.f};

    for (int kt = 0; kt < 8; ++kt) {
        s16x8 ah  = *(const s16x8*)(Qh + GROW(qa) + kt * 32 + fk);
        s16x8 al_ = *(const s16x8*)(Ql + GROW(qa) + kt * 32 + fk);
        #pragma unroll
        for (int nf = 0; nf < 8; ++nf) {
            const int l = nf * 16 + fr;
            s16x8 bh = *(const s16x8*)(Kh + GROW(l) + kt * 32 + fk);
            acc[nf] = __builtin_amdgcn_mfma_f32_16x16x32_bf16(ah,  bh, acc[nf], 0, 0, 0);
            acc[nf] = __builtin_amdgcn_mfma_f32_16x16x32_bf16(al_, bh, acc[nf], 0, 0, 0);
        }
    }

    #pragma unroll
    for (int r = 0; r < 4; ++r) {
        const int q    = q0 + 16 * w + g * 4 + r;
        const int qloc = 16 * w + g * 4 + r;
        float v[8];
        float m = -1e30f;
        #pragma unroll
        for (int nf = 0; nf < 8; ++nf) {
            const int l = nf * 16 + fr;
            v[nf] = (l > q) ? acc[nf][r] * 0.0625f : -1e30f;
            m = fmaxf(m, v[nf]);
        }
        #pragma unroll
        for (int o = 8; o > 0; o >>= 1) m = fmaxf(m, __shfl_xor(m, o));
        float s = 0.f;
        #pragma unroll
        for (int nf = 0; nf < 8; ++nf) { v[nf] = expf(v[nf] - m); s += v[nf]; }
        #pragma unroll
        for (int o = 8; o > 0; o >>= 1) s += __shfl_xor(s, o);
        const float inv = 1.f / s;
        #pragma unroll
        for (int nf = 0; nf < 8; ++nf) {
            u16 hh, ll;
            split2(v[nf] * inv, hh, ll);
            att_h[qloc * 136 + nf * 16 + fr] = hh;
            att_l[qloc * 136 + nf * 16 + fr] = ll;
        }
    }

    // ---------------- Phase 2: QE (V.E^T) + skew -> S ----------------
    #pragma unroll
    for (int nf = 0; nf < 8; ++nf) acc[nf] = (f32x4){0.f, 0.f, 0.f, 0.f};

    for (int kt = 0; kt < 8; ++kt) {
        s16x8 ah  = *(const s16x8*)(Vh + GROW(qa) + kt * 32 + fk);
        s16x8 al_ = *(const s16x8*)(Vl + GROW(qa) + kt * 32 + fk);
        #pragma unroll
        for (int nf = 0; nf < 8; ++nf) {
            const int j = nf * 16 + fr;
            s16x8 bh = *(const s16x8*)(Eh + ((size_t)(h * 128 + j)) * 256 + kt * 32 + fk);
            acc[nf] = __builtin_amdgcn_mfma_f32_16x16x32_bf16(ah,  bh, acc[nf], 0, 0, 0);
            acc[nf] = __builtin_amdgcn_mfma_f32_16x16x32_bf16(al_, bh, acc[nf], 0, 0, 0);
        }
    }

    #pragma unroll
    for (int r = 0; r < 4; ++r) {
        const int q    = q0 + 16 * w + g * 4 + r;
        const int qloc = 16 * w + g * 4 + r;
        #pragma unroll
        for (int nf = 0; nf < 8; ++nf) {
            const int j  = nf * 16 + fr;
            const int lt = j - 127 + q;
            float sv = acc[nf][r];
            if (q == 127) sv += 0.0078125f;
            if (lt >= 0) {
                u16 hh, ll;
                split2(sv, hh, ll);
                att_h[qloc * 136 + lt] = hh;
                att_l[qloc * 136 + lt] = ll;
            }
        }
    }

    // ---------------- Phase 3: Z = att . V (quartered Vt) ----------------
    f32x4 az[16];
    #pragma unroll
    for (int nf = 0; nf < 16; ++nf) az[nf] = (f32x4){0.f, 0.f, 0.f, 0.f};

    const int lrow = tid & 63, ec4 = tid >> 6;
    #pragma unroll
    for (int lh = 0; lh < 2; ++lh) {
        #pragma unroll
        for (int eh = 0; eh < 2; ++eh) {
            __syncthreads();
            {
                const u16* vsrc = Vh + GROW(lh * 64 + lrow) + eh * 128 + ec4 * 32;
                #pragma unroll
                for (int c = 0; c < 4; ++c) {
                    uint4 pk = *(const uint4*)(vsrc + c * 8);
                    const u16* t = (const u16*)&pk;
                    const int e = ec4 * 32 + c * 8;
                    #pragma unroll
                    for (int j = 0; j < 8; ++j) Vt[(e + j) * 72 + lrow] = t[j];
                }
            }
            __syncthreads();
            #pragma unroll
            for (int kt = 0; kt < 2; ++kt) {
                const int lg = lh * 64 + kt * 32 + fk;
                s16x8 ah  = *(const s16x8*)(att_h + (16 * w + fr) * 136 + lg);
                s16x8 al_ = *(const s16x8*)(att_l + (16 * w + fr) * 136 + lg);
                #pragma unroll
                for (int nf = 0; nf < 8; ++nf) {
                    s16x8 bh = *(const s16x8*)(Vt + (nf * 16 + fr) * 72 + kt * 32 + fk);
                    az[eh * 8 + nf] = __builtin_amdgcn_mfma_f32_16x16x32_bf16(ah,  bh, az[eh * 8 + nf], 0, 0, 0);
                    az[eh * 8 + nf] = __builtin_amdgcn_mfma_f32_16x16x32_bf16(al_, bh, az[eh * 8 + nf], 0, 0, 0);
                }
            }
        }
    }

    #pragma unroll
    for (int r = 0; r < 4; ++r) {
        const int q = q0 + 16 * w + g * 4 + r;
        #pragma unroll
        for (int nf = 0; nf < 16; ++nf) {
            u16 hh, ll;
            split2(az[nf][r], hh, ll);
            Zh[GROW(q) + nf * 16 + fr] = hh;
            Zl[GROW(q) + nf * 16 + fr] = ll;
        }
    }
    #undef GROW
}

// ---------------------------------------------------------------------------
extern "C" void kernel_launch(void* const* d_in, const int* in_sizes, int n_in,
                              void* d_out, int out_size, void* d_ws, size_t ws_size,
                              hipStream_t stream)
{
    const float* x  = (const float*)d_in[0];
    const float* ei = (const float*)d_in[1];
    const int L = 1;   // only the last layer affects the output
    const float* Wv  = (const float*)d_in[2]  + (size_t)L*EMB*EMB;
    const float* bv  = (const float*)d_in[3]  + (size_t)L*EMB;
    const float* Wk  = (const float*)d_in[4]  + (size_t)L*EMB*EMB;
    const float* bk  = (const float*)d_in[5]  + (size_t)L*EMB;
    const float* Wq  = (const float*)d_in[6]  + (size_t)L*EMB*EMB;
    const float* bq  = (const float*)d_in[7]  + (size_t)L*EMB;
    const float* Ep  = (const float*)d_in[8]  + (size_t)L*NH*SEQL*EMB;
    const float* Wo  = (const float*)d_in[9]  + (size_t)L*EMB*EMB;
    const float* bo  = (const float*)d_in[10] + (size_t)L*EMB;
    const float* b2w = (const float*)d_in[11] + (size_t)L*CCH;
    const float* b2b = (const float*)d_in[12] + (size_t)L*CCH;
    const float* b3w = (const float*)d_in[13] + (size_t)L*CCH;
    const float* b3b = (const float*)d_in[14] + (size_t)L*CCH;
    const float* fW1 = (const float*)d_in[15] + (size_t)L*EMB*EMB;
    const float* fb1 = (const float*)d_in[16] + (size_t)L*EMB;
    const float* fW2 = (const float*)d_in[17] + (size_t)L*EMB*EMB;
    const float* fb2 = (const float*)d_in[18] + (size_t)L*EMB;
    const float* fcW = (const float*)d_in[19];
    const float* fcb = (const float*)d_in[20];

    // workspace map
    float* W0f  = (float*)d_ws;                    // region 0: 2 planes
    float* W1f  = W0f + SZ;                        // region 1: 2 planes
    float* stat = W1f + SZ;                        // 16384 floats reserved
    u16*   Wt   = (u16*)(stat + 16384);            // 7 x 131072 u16
    u16*   ehb  = Wt + (size_t)7 * 131072;         // 262144 u16

    u16* Vh  = (u16*)W0f;      u16* Vl  = Vh + SZ;     // -> later f1h/f1l
    u16* kh  = (u16*)W1f;                               // first plane of region 1
    u16* r2h = (u16*)W1f;      u16* r2l = r2h + SZ;    // also r3 (in-place)
    u16* Qh  = (u16*)d_out;    u16* Ql  = Qh + SZ;     // -> Zh/Zl -> final fp32
    float* OUT = (float*)d_out;

    float* s2 = stat;        float* q2 = stat + 1024;
    float* s3 = stat + 2048; float* q3 = stat + 3072;
    float* a2 = stat + 4096; float* b2 = stat + 5120;
    float* a3 = stat + 6144; float* b3 = stat + 7168;
    float* cs1 = stat + 8192; float* csf = stat + 8448;

    auto slotH = [&](int m){ return Wt + (size_t)m * 131072; };
    auto slotL = [&](int m){ return Wt + (size_t)m * 131072 + 65536; };

    dim3 blk(256);
    zero_stats<<<16, blk, 0, stream>>>(stat);
    wtconv<<<896, blk, 0, stream>>>(Wv, Wk, Wq, Wo, fW1, fW2, fcW, Wt);
    colsum_k<<<2, blk, 0, stream>>>(fW1, fcW, cs1, csf);
    prep_eh<<<256, blk, 0, stream>>>(Ep, ehb);

    // vals -> V planes
    mgemm<0,0,0,0,0,1><<<1024, blk, 0, stream>>>(ei, nullptr, nullptr,
        slotH(0), slotL(0), bv, nullptr, nullptr, nullptr,
        nullptr, nullptr, nullptr, nullptr, nullptr, nullptr, nullptr,
        nullptr, Vh, Vl);
    // keys -> bf16-hi
    mgemm<0,0,0,0,0,2><<<1024, blk, 0, stream>>>(ei, nullptr, nullptr,
        slotH(1), slotL(1), bk, nullptr, nullptr, nullptr,
        nullptr, nullptr, nullptr, nullptr, nullptr, nullptr, nullptr,
        nullptr, kh, nullptr);
    // qrys -> Q planes (d_out)
    mgemm<0,0,0,0,0,1><<<1024, blk, 0, stream>>>(x, nullptr, nullptr,
        slotH(2), slotL(2), bq, nullptr, nullptr, nullptr,
        nullptr, nullptr, nullptr, nullptr, nullptr, nullptr, nullptr,
        nullptr, Qh, Ql);

    // attention: z planes in-place over Q planes
    attn_mfma<<<1024, blk, 0, stream>>>(Qh, Ql, kh, Vh, Vl, ehb, Qh, Ql);

    // r2 = z@Wo + bo + x  (+bn2 stats) -> r2 planes (over kh, dead)
    mgemm<1,0,0,1,1,1><<<1024, blk, 0, stream>>>(nullptr, Qh, Ql,
        slotH(3), slotL(3), bo, x, nullptr, nullptr,
        nullptr, nullptr, nullptr, nullptr, nullptr, s2, q2,
        nullptr, r2h, r2l);
    bn_finalize<<<4, blk, 0, stream>>>(s2, q2, b2w, b2b, a2, b2);

    // ff1 = leaky(BN2(r2)@fW1 + fb1) -> f1 planes (over V planes, dead)
    mgemm<1,1,1,0,0,1><<<1024, blk, 0, stream>>>(nullptr, r2h, r2l,
        slotH(4), slotL(4), fb1, nullptr, nullptr, nullptr,
        a2, b2, cs1, nullptr, nullptr, nullptr, nullptr,
        nullptr, Vh, Vl);

    // r3 = ff1@fW2 + fb2 + BN2(r2)  (+bn3 stats) -> in-place over r2 planes
    mgemm<1,0,0,2,1,1><<<1024, blk, 0, stream>>>(nullptr, Vh, Vl,
        slotH(5), slotL(5), fb2, nullptr, r2h, r2l,
        nullptr, nullptr, nullptr, a2, b2, s3, q3,
        nullptr, r2h, r2l);
    bn_finalize<<<4, blk, 0, stream>>>(s3, q3, b3w, b3b, a3, b3);

    // final = BN3(r3)@fcW + fcb -> fp32 d_out (z planes dead)
    mgemm<1,1,0,0,0,0><<<1024, blk, 0, stream>>>(nullptr, r2h, r2l,
        slotH(6), slotL(6), fcb, nullptr, nullptr, nullptr,
        a3, b3, csf, nullptr, nullptr, nullptr, nullptr,
        OUT, nullptr, nullptr);
}